// Round 1
// baseline (2145.047 us; speedup 1.0000x reference)
//
#include <hip/hip_runtime.h>

// Problem constants (from reference)
constexpr int BGRAPHS = 8;
constexpr int NNODES  = 10000;
constexpr int NEDGES  = 320000;
constexpr int CH      = 128;     // C_IN == C_OUT == 128

// ---------------------------------------------------------------------------
// Kernel 0: zero the accumulator (d_out doubles as the ax accumulator).
// ---------------------------------------------------------------------------
__global__ __launch_bounds__(256) void zero_kernel(float* __restrict__ p, int n4) {
    int i = blockIdx.x * blockDim.x + threadIdx.x;
    int stride = gridDim.x * blockDim.x;
    float4 z = make_float4(0.f, 0.f, 0.f, 0.f);
    for (int j = i; j < n4; j += stride) {
        reinterpret_cast<float4*>(p)[j] = z;
    }
}

// ---------------------------------------------------------------------------
// Kernel 1: edge scatter.  One wave (64 lanes) per edge; lane l handles
// channels [2l, 2l+1].  Gather x[b, col] (coalesced float2 = 512B/wave),
// scale by val, atomicAdd into ax[b, row].
// ---------------------------------------------------------------------------
__global__ __launch_bounds__(256) void scatter_kernel(
    const float* __restrict__ x, const int* __restrict__ rows,
    const int* __restrict__ cols, const float* __restrict__ vals,
    float* __restrict__ ax) {
    const int lane = threadIdx.x & 63;
    int wid = (blockIdx.x * blockDim.x + threadIdx.x) >> 6;
    const int nw = (gridDim.x * blockDim.x) >> 6;
    const int total = BGRAPHS * NEDGES;
    for (int e = wid; e < total; e += nw) {
        int b = e / NEDGES;               // compile-time magic-mul
        int r = rows[e];
        int c = cols[e];
        float v = vals[e];
        const float2 m =
            reinterpret_cast<const float2*>(x + (size_t)(b * NNODES + c) * CH)[lane];
        float* dst = ax + (size_t)(b * NNODES + r) * CH + 2 * lane;
        atomicAdd(dst,     v * m.x);
        atomicAdd(dst + 1, v * m.y);
    }
}

// ---------------------------------------------------------------------------
// Kernel 2: in-place dense transform + bias + ReLU.
//   out_row = relu(ax_row @ W + b)
// W (128x128 f32 = 64KB) lives in LDS.  256 threads: 8 rows per iteration,
// 32 threads per row, each thread computes 4 contiguous output channels.
// ---------------------------------------------------------------------------
__global__ __launch_bounds__(256) void transform_kernel(
    float* __restrict__ io, const float* __restrict__ W,
    const float* __restrict__ bias, int totalRows) {
    __shared__ float Ws[CH * CH];          // 64 KB
    __shared__ float rbuf[8][CH];          // 4 KB

    // cooperative W load (coalesced float4)
    for (int i = threadIdx.x * 4; i < CH * CH; i += blockDim.x * 4) {
        *reinterpret_cast<float4*>(&Ws[i]) =
            *reinterpret_cast<const float4*>(&W[i]);
    }
    const int rs = threadIdx.x >> 5;       // row slot 0..7
    const int o4 = threadIdx.x & 31;       // output quad 0..31
    const float4 bias4 = *reinterpret_cast<const float4*>(&bias[4 * o4]);
    __syncthreads();

    for (int base = blockIdx.x * 8; base < totalRows; base += gridDim.x * 8) {
        // stage 8 rows into LDS (totalRows = 80000 is divisible by 8)
        const int row = base + rs;
        *reinterpret_cast<float4*>(&rbuf[rs][4 * o4]) =
            *reinterpret_cast<const float4*>(&io[(size_t)row * CH + 4 * o4]);
        __syncthreads();

        float4 acc = bias4;
        #pragma unroll 8
        for (int c = 0; c < CH; ++c) {
            const float rv = rbuf[rs][c];                       // broadcast read
            const float4 w4 =
                *reinterpret_cast<const float4*>(&Ws[c * CH + 4 * o4]);  // b128
            acc.x += rv * w4.x;
            acc.y += rv * w4.y;
            acc.z += rv * w4.z;
            acc.w += rv * w4.w;
        }
        acc.x = fmaxf(acc.x, 0.f);
        acc.y = fmaxf(acc.y, 0.f);
        acc.z = fmaxf(acc.z, 0.f);
        acc.w = fmaxf(acc.w, 0.f);
        *reinterpret_cast<float4*>(&io[(size_t)row * CH + 4 * o4]) = acc;
        __syncthreads();
    }
}

// ---------------------------------------------------------------------------
extern "C" void kernel_launch(void* const* d_in, const int* in_sizes, int n_in,
                              void* d_out, int out_size, void* d_ws, size_t ws_size,
                              hipStream_t stream) {
    const float* x    = (const float*)d_in[0];
    const int*   rows = (const int*)  d_in[1];
    const int*   cols = (const int*)  d_in[2];
    const float* vals = (const float*)d_in[3];
    const float* W    = (const float*)d_in[4];
    const float* bias = (const float*)d_in[5];
    float* out = (float*)d_out;

    const int totalRows = BGRAPHS * NNODES;          // 80000
    const int n4 = out_size / 4;                     // 2.56M float4

    zero_kernel<<<2048, 256, 0, stream>>>(out, n4);
    scatter_kernel<<<20480, 256, 0, stream>>>(x, rows, cols, vals, out);
    transform_kernel<<<2048, 256, 0, stream>>>(out, W, bias, totalRows);
}

// Round 2
// 732.248 us; speedup vs baseline: 2.9294x; 2.9294x over previous
//
#include <hip/hip_runtime.h>

// Problem constants (from reference)
constexpr int BGRAPHS = 8;
constexpr int NNODES  = 10000;
constexpr int NEDGES  = 320000;
constexpr int CH      = 128;     // C_IN == C_OUT == 128
constexpr int TOTROWS = BGRAPHS * NNODES;   // 80000
constexpr int TOTEDGE = BGRAPHS * NEDGES;   // 2560000

// ---------------------------------------------------------------------------
// Utility: zero an int buffer
// ---------------------------------------------------------------------------
__global__ __launch_bounds__(256) void zero_int_kernel(int* __restrict__ p, int n) {
    int i = blockIdx.x * blockDim.x + threadIdx.x;
    if (i < n) p[i] = 0;
}

__global__ __launch_bounds__(256) void zero_f4_kernel(float* __restrict__ p, int n4) {
    int i = blockIdx.x * blockDim.x + threadIdx.x;
    int stride = gridDim.x * blockDim.x;
    float4 z = make_float4(0.f, 0.f, 0.f, 0.f);
    for (int j = i; j < n4; j += stride) reinterpret_cast<float4*>(p)[j] = z;
}

// ---------------------------------------------------------------------------
// Phase A: per-destination-row edge histogram (int atomics, 80k counters)
// ---------------------------------------------------------------------------
__global__ __launch_bounds__(256) void hist_kernel(
    const int* __restrict__ rows, int* __restrict__ cnt) {
    int i = blockIdx.x * blockDim.x + threadIdx.x;
    int stride = gridDim.x * blockDim.x;
    for (int e = i; e < TOTEDGE; e += stride) {
        int b = e / NEDGES;
        atomicAdd(&cnt[b * NNODES + rows[e]], 1);
    }
}

// ---------------------------------------------------------------------------
// Phase B: single-block exclusive scan of cnt[80000] -> row_ptr[80001], cursor
// 1024 threads, 79 elements each (sequential), Hillis-Steele over partials.
// ---------------------------------------------------------------------------
__global__ __launch_bounds__(1024) void scan_kernel(
    const int* __restrict__ cnt, int* __restrict__ row_ptr,
    int* __restrict__ cursor) {
    __shared__ int ssum[1024];
    const int t = threadIdx.x;
    const int PER = (TOTROWS + 1023) / 1024;   // 79
    const int base = t * PER;
    int s = 0;
    for (int i = 0; i < PER; ++i) {
        int idx = base + i;
        if (idx < TOTROWS) s += cnt[idx];
    }
    ssum[t] = s;
    __syncthreads();
    // inclusive Hillis-Steele scan
    for (int off = 1; off < 1024; off <<= 1) {
        int v = (t >= off) ? ssum[t - off] : 0;
        __syncthreads();
        ssum[t] += v;
        __syncthreads();
    }
    int run = ssum[t] - s;   // exclusive prefix for this thread's range
    for (int i = 0; i < PER; ++i) {
        int idx = base + i;
        if (idx < TOTROWS) {
            int c = cnt[idx];
            row_ptr[idx] = run;
            cursor[idx]  = run;
            run += c;
        }
    }
    if (t == 1023) row_ptr[TOTROWS] = ssum[1023];
}

// ---------------------------------------------------------------------------
// Phase C: reorder edges into CSR order.  edata[pos] = {col_bits, val}
// ---------------------------------------------------------------------------
__global__ __launch_bounds__(256) void reorder_kernel(
    const int* __restrict__ rows, const int* __restrict__ cols,
    const float* __restrict__ vals, int* __restrict__ cursor,
    float2* __restrict__ edata) {
    int i = blockIdx.x * blockDim.x + threadIdx.x;
    int stride = gridDim.x * blockDim.x;
    for (int e = i; e < TOTEDGE; e += stride) {
        int b = e / NEDGES;
        int grow = b * NNODES + rows[e];
        int gcol = b * NNODES + cols[e];
        int pos = atomicAdd(&cursor[grow], 1);
        edata[pos] = make_float2(__int_as_float(gcol), vals[e]);
    }
}

// ---------------------------------------------------------------------------
// Phase D: gather SpMM.  One wave per output row; lane l owns channels
// [2l, 2l+1] (float2).  Accumulate in registers, write once.
// ---------------------------------------------------------------------------
__global__ __launch_bounds__(256) void gather_kernel(
    const float* __restrict__ x, const int* __restrict__ row_ptr,
    const float2* __restrict__ edata, float* __restrict__ ax) {
    const int lane = threadIdx.x & 63;
    const int grow = blockIdx.x * 4 + (threadIdx.x >> 6);   // 20000 blocks * 4
    if (grow >= TOTROWS) return;
    const int start = row_ptr[grow];
    const int end   = row_ptr[grow + 1];
    const float2* xf2 = reinterpret_cast<const float2*>(x);

    float2 acc0 = make_float2(0.f, 0.f);
    float2 acc1 = make_float2(0.f, 0.f);
    int e = start;
    for (; e + 1 < end; e += 2) {
        float2 m0 = edata[e];
        float2 m1 = edata[e + 1];
        int c0 = __float_as_int(m0.x);
        int c1 = __float_as_int(m1.x);
        float2 x0 = xf2[(size_t)c0 * 64 + lane];
        float2 x1 = xf2[(size_t)c1 * 64 + lane];
        acc0.x += m0.y * x0.x; acc0.y += m0.y * x0.y;
        acc1.x += m1.y * x1.x; acc1.y += m1.y * x1.y;
    }
    if (e < end) {
        float2 m0 = edata[e];
        int c0 = __float_as_int(m0.x);
        float2 x0 = xf2[(size_t)c0 * 64 + lane];
        acc0.x += m0.y * x0.x; acc0.y += m0.y * x0.y;
    }
    acc0.x += acc1.x; acc0.y += acc1.y;
    reinterpret_cast<float2*>(ax)[(size_t)grow * 64 + lane] = acc0;
}

// ---------------------------------------------------------------------------
// Phase E: in-place dense transform + bias + ReLU (unchanged from round 1)
// ---------------------------------------------------------------------------
__global__ __launch_bounds__(256) void transform_kernel(
    float* __restrict__ io, const float* __restrict__ W,
    const float* __restrict__ bias, int totalRows) {
    __shared__ float Ws[CH * CH];          // 64 KB
    __shared__ float rbuf[8][CH];          // 4 KB

    for (int i = threadIdx.x * 4; i < CH * CH; i += blockDim.x * 4) {
        *reinterpret_cast<float4*>(&Ws[i]) =
            *reinterpret_cast<const float4*>(&W[i]);
    }
    const int rs = threadIdx.x >> 5;
    const int o4 = threadIdx.x & 31;
    const float4 bias4 = *reinterpret_cast<const float4*>(&bias[4 * o4]);
    __syncthreads();

    for (int base = blockIdx.x * 8; base < totalRows; base += gridDim.x * 8) {
        const int row = base + rs;
        *reinterpret_cast<float4*>(&rbuf[rs][4 * o4]) =
            *reinterpret_cast<const float4*>(&io[(size_t)row * CH + 4 * o4]);
        __syncthreads();

        float4 acc = bias4;
        #pragma unroll 8
        for (int c = 0; c < CH; ++c) {
            const float rv = rbuf[rs][c];
            const float4 w4 =
                *reinterpret_cast<const float4*>(&Ws[c * CH + 4 * o4]);
            acc.x += rv * w4.x;
            acc.y += rv * w4.y;
            acc.z += rv * w4.z;
            acc.w += rv * w4.w;
        }
        acc.x = fmaxf(acc.x, 0.f);
        acc.y = fmaxf(acc.y, 0.f);
        acc.z = fmaxf(acc.z, 0.f);
        acc.w = fmaxf(acc.w, 0.f);
        *reinterpret_cast<float4*>(&io[(size_t)row * CH + 4 * o4]) = acc;
        __syncthreads();
    }
}

// ---------------------------------------------------------------------------
// Fallback (round-1 atomic path) if ws is too small
// ---------------------------------------------------------------------------
__global__ __launch_bounds__(256) void scatter_kernel(
    const float* __restrict__ x, const int* __restrict__ rows,
    const int* __restrict__ cols, const float* __restrict__ vals,
    float* __restrict__ ax) {
    const int lane = threadIdx.x & 63;
    int wid = (blockIdx.x * blockDim.x + threadIdx.x) >> 6;
    const int nw = (gridDim.x * blockDim.x) >> 6;
    for (int e = wid; e < TOTEDGE; e += nw) {
        int b = e / NEDGES;
        int r = rows[e];
        int c = cols[e];
        float v = vals[e];
        const float2 m =
            reinterpret_cast<const float2*>(x + (size_t)(b * NNODES + c) * CH)[lane];
        float* dst = ax + (size_t)(b * NNODES + r) * CH + 2 * lane;
        atomicAdd(dst,     v * m.x);
        atomicAdd(dst + 1, v * m.y);
    }
}

// ---------------------------------------------------------------------------
extern "C" void kernel_launch(void* const* d_in, const int* in_sizes, int n_in,
                              void* d_out, int out_size, void* d_ws, size_t ws_size,
                              hipStream_t stream) {
    const float* x    = (const float*)d_in[0];
    const int*   rows = (const int*)  d_in[1];
    const int*   cols = (const int*)  d_in[2];
    const float* vals = (const float*)d_in[3];
    const float* W    = (const float*)d_in[4];
    const float* bias = (const float*)d_in[5];
    float* out = (float*)d_out;

    // ws layout: cnt[80000] | row_ptr[80001(+pad 80008)] | cursor[80000] | edata[2.56M float2]
    const size_t off_cnt    = 0;
    const size_t off_rowptr = off_cnt + (size_t)TOTROWS * 4;
    const size_t off_cursor = off_rowptr + (size_t)(TOTROWS + 8) * 4;
    const size_t off_edata  = off_cursor + (size_t)TOTROWS * 4;
    const size_t need       = off_edata + (size_t)TOTEDGE * 8;

    if (ws_size >= need) {
        int*    cnt     = (int*)   ((char*)d_ws + off_cnt);
        int*    row_ptr = (int*)   ((char*)d_ws + off_rowptr);
        int*    cursor  = (int*)   ((char*)d_ws + off_cursor);
        float2* edata   = (float2*)((char*)d_ws + off_edata);

        zero_int_kernel<<<(TOTROWS + 255) / 256, 256, 0, stream>>>(cnt, TOTROWS);
        hist_kernel<<<4096, 256, 0, stream>>>(rows, cnt);
        scan_kernel<<<1, 1024, 0, stream>>>(cnt, row_ptr, cursor);
        reorder_kernel<<<4096, 256, 0, stream>>>(rows, cols, vals, cursor, edata);
        gather_kernel<<<TOTROWS / 4, 256, 0, stream>>>(x, row_ptr, edata, out);
        transform_kernel<<<2048, 256, 0, stream>>>(out, W, bias, TOTROWS);
    } else {
        // fallback: atomic scatter path
        zero_f4_kernel<<<2048, 256, 0, stream>>>(out, out_size / 4);
        scatter_kernel<<<20480, 256, 0, stream>>>(x, rows, cols, vals, out);
        transform_kernel<<<2048, 256, 0, stream>>>(out, W, bias, TOTROWS);
    }
}

// Round 3
// 496.245 us; speedup vs baseline: 4.3226x; 1.4756x over previous
//
#include <hip/hip_runtime.h>

// Problem constants (from reference)
constexpr int BGRAPHS = 8;
constexpr int NNODES  = 10000;
constexpr int NEDGES  = 320000;
constexpr int CH      = 128;     // C_IN == C_OUT == 128
constexpr int TOTROWS = BGRAPHS * NNODES;   // 80000
constexpr int TOTEDGE = BGRAPHS * NEDGES;   // 2560000
constexpr int SCAN_BLOCKS = (TOTROWS + 255) / 256;  // 313

// ---------------------------------------------------------------------------
__global__ __launch_bounds__(256) void zero_int_kernel(int* __restrict__ p, int n) {
    int i = blockIdx.x * blockDim.x + threadIdx.x;
    if (i < n) p[i] = 0;
}

__global__ __launch_bounds__(256) void zero_f4_kernel(float* __restrict__ p, int n4) {
    int i = blockIdx.x * blockDim.x + threadIdx.x;
    int stride = gridDim.x * blockDim.x;
    float4 z = make_float4(0.f, 0.f, 0.f, 0.f);
    for (int j = i; j < n4; j += stride) reinterpret_cast<float4*>(p)[j] = z;
}

// ---------------------------------------------------------------------------
// Phase A: per-destination-row edge histogram.  4 edges/thread via int4.
// grid = TOTEDGE/4/256 = 2500 blocks exactly.
// ---------------------------------------------------------------------------
__global__ __launch_bounds__(256) void hist_kernel(
    const int* __restrict__ rows, int* __restrict__ cnt) {
    int e0 = (blockIdx.x * blockDim.x + threadIdx.x) * 4;
    int b = e0 / NEDGES;               // 4-edge packet never crosses graph bound
    int base = b * NNODES;
    int4 r4 = *reinterpret_cast<const int4*>(&rows[e0]);
    atomicAdd(&cnt[base + r4.x], 1);
    atomicAdd(&cnt[base + r4.y], 1);
    atomicAdd(&cnt[base + r4.z], 1);
    atomicAdd(&cnt[base + r4.w], 1);
}

// ---------------------------------------------------------------------------
// Phase B: hierarchical exclusive scan of cnt[80000].
//   scan1: per-block (256-chunk) sums -> bsum[313]
//   scan2: single small block scans bsum -> ebsum (exclusive)
//   scan3: per-block scan + global offset -> row_ptr, cursor
// ---------------------------------------------------------------------------
__global__ __launch_bounds__(256) void scan1_kernel(
    const int* __restrict__ cnt, int* __restrict__ bsum) {
    __shared__ int ws[4];
    int idx = blockIdx.x * 256 + threadIdx.x;
    int v = (idx < TOTROWS) ? cnt[idx] : 0;
    #pragma unroll
    for (int off = 32; off > 0; off >>= 1) v += __shfl_down(v, off);
    if ((threadIdx.x & 63) == 0) ws[threadIdx.x >> 6] = v;
    __syncthreads();
    if (threadIdx.x == 0) bsum[blockIdx.x] = ws[0] + ws[1] + ws[2] + ws[3];
}

__global__ __launch_bounds__(512) void scan2_kernel(
    const int* __restrict__ bsum, int* __restrict__ ebsum) {
    __shared__ int s[512];
    int t = threadIdx.x;
    int v = (t < SCAN_BLOCKS) ? bsum[t] : 0;
    s[t] = v;
    __syncthreads();
    for (int off = 1; off < 512; off <<= 1) {
        int u = (t >= off) ? s[t - off] : 0;
        __syncthreads();
        s[t] += u;
        __syncthreads();
    }
    if (t < SCAN_BLOCKS) ebsum[t] = s[t] - v;   // exclusive
}

__global__ __launch_bounds__(256) void scan3_kernel(
    const int* __restrict__ cnt, const int* __restrict__ ebsum,
    int* __restrict__ row_ptr, int* __restrict__ cursor) {
    __shared__ int s[256];
    int t = threadIdx.x;
    int idx = blockIdx.x * 256 + t;
    int v = (idx < TOTROWS) ? cnt[idx] : 0;
    s[t] = v;
    __syncthreads();
    for (int off = 1; off < 256; off <<= 1) {
        int u = (t >= off) ? s[t - off] : 0;
        __syncthreads();
        s[t] += u;
        __syncthreads();
    }
    if (idx < TOTROWS) {
        int p = ebsum[blockIdx.x] + s[t] - v;    // global exclusive prefix
        row_ptr[idx] = p;
        cursor[idx]  = p;
    }
    if (idx == 0) row_ptr[TOTROWS] = TOTEDGE;    // constant by construction
}

// ---------------------------------------------------------------------------
// Phase C: reorder edges into CSR order.  4 edges/thread.
// edata[pos] = {col_bits, val}
// ---------------------------------------------------------------------------
__global__ __launch_bounds__(256) void reorder_kernel(
    const int* __restrict__ rows, const int* __restrict__ cols,
    const float* __restrict__ vals, int* __restrict__ cursor,
    float2* __restrict__ edata) {
    int e0 = (blockIdx.x * blockDim.x + threadIdx.x) * 4;
    int b = e0 / NEDGES;
    int base = b * NNODES;
    int4   r4 = *reinterpret_cast<const int4*>(&rows[e0]);
    int4   c4 = *reinterpret_cast<const int4*>(&cols[e0]);
    float4 v4 = *reinterpret_cast<const float4*>(&vals[e0]);
    int p0 = atomicAdd(&cursor[base + r4.x], 1);
    edata[p0] = make_float2(__int_as_float(base + c4.x), v4.x);
    int p1 = atomicAdd(&cursor[base + r4.y], 1);
    edata[p1] = make_float2(__int_as_float(base + c4.y), v4.y);
    int p2 = atomicAdd(&cursor[base + r4.z], 1);
    edata[p2] = make_float2(__int_as_float(base + c4.z), v4.z);
    int p3 = atomicAdd(&cursor[base + r4.w], 1);
    edata[p3] = make_float2(__int_as_float(base + c4.w), v4.w);
}

// ---------------------------------------------------------------------------
// Phase D: xW = x @ W  (dense, W in LDS, 8 rows/block-iter, float4 everywhere)
// ---------------------------------------------------------------------------
__global__ __launch_bounds__(256) void xw_kernel(
    const float* __restrict__ x, const float* __restrict__ W,
    float* __restrict__ xw) {
    __shared__ float Ws[CH * CH];          // 64 KB
    __shared__ float rbuf[8][CH];          // 4 KB

    for (int i = threadIdx.x * 4; i < CH * CH; i += blockDim.x * 4) {
        *reinterpret_cast<float4*>(&Ws[i]) =
            *reinterpret_cast<const float4*>(&W[i]);
    }
    const int rs = threadIdx.x >> 5;
    const int o4 = threadIdx.x & 31;
    __syncthreads();

    for (int base = blockIdx.x * 8; base < TOTROWS; base += gridDim.x * 8) {
        const int row = base + rs;
        *reinterpret_cast<float4*>(&rbuf[rs][4 * o4]) =
            *reinterpret_cast<const float4*>(&x[(size_t)row * CH + 4 * o4]);
        __syncthreads();

        float4 acc = make_float4(0.f, 0.f, 0.f, 0.f);
        #pragma unroll 8
        for (int c = 0; c < CH; ++c) {
            const float rv = rbuf[rs][c];
            const float4 w4 =
                *reinterpret_cast<const float4*>(&Ws[c * CH + 4 * o4]);
            acc.x += rv * w4.x;
            acc.y += rv * w4.y;
            acc.z += rv * w4.z;
            acc.w += rv * w4.w;
        }
        *reinterpret_cast<float4*>(&xw[(size_t)row * CH + 4 * o4]) = acc;
        __syncthreads();
    }
}

// ---------------------------------------------------------------------------
// Phase E: fused gather + bias + ReLU.  One wave per output row, lane l owns
// channels [2l, 2l+1].  out_row = relu(sum_e v*xW[col] + bias)
// ---------------------------------------------------------------------------
__global__ __launch_bounds__(256) void gather_fused_kernel(
    const float* __restrict__ xw, const int* __restrict__ row_ptr,
    const float2* __restrict__ edata, const float* __restrict__ bias,
    float* __restrict__ out) {
    const int lane = threadIdx.x & 63;
    const int grow = blockIdx.x * 4 + (threadIdx.x >> 6);
    if (grow >= TOTROWS) return;
    const int start = row_ptr[grow];
    const int end   = row_ptr[grow + 1];
    const float2* xf2 = reinterpret_cast<const float2*>(xw);

    float2 a0 = make_float2(0.f, 0.f), a1 = a0, a2 = a0, a3 = a0;
    int e = start;
    for (; e + 3 < end; e += 4) {
        float2 m0 = edata[e];
        float2 m1 = edata[e + 1];
        float2 m2 = edata[e + 2];
        float2 m3 = edata[e + 3];
        float2 x0 = xf2[(size_t)__float_as_int(m0.x) * 64 + lane];
        float2 x1 = xf2[(size_t)__float_as_int(m1.x) * 64 + lane];
        float2 x2 = xf2[(size_t)__float_as_int(m2.x) * 64 + lane];
        float2 x3 = xf2[(size_t)__float_as_int(m3.x) * 64 + lane];
        a0.x += m0.y * x0.x; a0.y += m0.y * x0.y;
        a1.x += m1.y * x1.x; a1.y += m1.y * x1.y;
        a2.x += m2.y * x2.x; a2.y += m2.y * x2.y;
        a3.x += m3.y * x3.x; a3.y += m3.y * x3.y;
    }
    for (; e < end; ++e) {
        float2 m = edata[e];
        float2 xv = xf2[(size_t)__float_as_int(m.x) * 64 + lane];
        a0.x += m.y * xv.x; a0.y += m.y * xv.y;
    }
    a0.x += a1.x + a2.x + a3.x;
    a0.y += a1.y + a2.y + a3.y;
    const float2 b2 = reinterpret_cast<const float2*>(bias)[lane];
    a0.x = fmaxf(a0.x + b2.x, 0.f);
    a0.y = fmaxf(a0.y + b2.y, 0.f);
    reinterpret_cast<float2*>(out)[(size_t)grow * 64 + lane] = a0;
}

// ---------------------------------------------------------------------------
// Fallback kernels (round-1/2 paths) in case ws is too small
// ---------------------------------------------------------------------------
__global__ __launch_bounds__(256) void transform_kernel(
    float* __restrict__ io, const float* __restrict__ W,
    const float* __restrict__ bias, int totalRows) {
    __shared__ float Ws[CH * CH];
    __shared__ float rbuf[8][CH];
    for (int i = threadIdx.x * 4; i < CH * CH; i += blockDim.x * 4) {
        *reinterpret_cast<float4*>(&Ws[i]) =
            *reinterpret_cast<const float4*>(&W[i]);
    }
    const int rs = threadIdx.x >> 5;
    const int o4 = threadIdx.x & 31;
    const float4 bias4 = *reinterpret_cast<const float4*>(&bias[4 * o4]);
    __syncthreads();
    for (int base = blockIdx.x * 8; base < totalRows; base += gridDim.x * 8) {
        const int row = base + rs;
        *reinterpret_cast<float4*>(&rbuf[rs][4 * o4]) =
            *reinterpret_cast<const float4*>(&io[(size_t)row * CH + 4 * o4]);
        __syncthreads();
        float4 acc = bias4;
        #pragma unroll 8
        for (int c = 0; c < CH; ++c) {
            const float rv = rbuf[rs][c];
            const float4 w4 =
                *reinterpret_cast<const float4*>(&Ws[c * CH + 4 * o4]);
            acc.x += rv * w4.x;
            acc.y += rv * w4.y;
            acc.z += rv * w4.z;
            acc.w += rv * w4.w;
        }
        acc.x = fmaxf(acc.x, 0.f);
        acc.y = fmaxf(acc.y, 0.f);
        acc.z = fmaxf(acc.z, 0.f);
        acc.w = fmaxf(acc.w, 0.f);
        *reinterpret_cast<float4*>(&io[(size_t)row * CH + 4 * o4]) = acc;
        __syncthreads();
    }
}

__global__ __launch_bounds__(256) void gather_plain_kernel(
    const float* __restrict__ x, const int* __restrict__ row_ptr,
    const float2* __restrict__ edata, float* __restrict__ ax) {
    const int lane = threadIdx.x & 63;
    const int grow = blockIdx.x * 4 + (threadIdx.x >> 6);
    if (grow >= TOTROWS) return;
    const int start = row_ptr[grow];
    const int end   = row_ptr[grow + 1];
    const float2* xf2 = reinterpret_cast<const float2*>(x);
    float2 a0 = make_float2(0.f, 0.f), a1 = a0;
    int e = start;
    for (; e + 1 < end; e += 2) {
        float2 m0 = edata[e];
        float2 m1 = edata[e + 1];
        float2 x0 = xf2[(size_t)__float_as_int(m0.x) * 64 + lane];
        float2 x1 = xf2[(size_t)__float_as_int(m1.x) * 64 + lane];
        a0.x += m0.y * x0.x; a0.y += m0.y * x0.y;
        a1.x += m1.y * x1.x; a1.y += m1.y * x1.y;
    }
    if (e < end) {
        float2 m = edata[e];
        float2 xv = xf2[(size_t)__float_as_int(m.x) * 64 + lane];
        a0.x += m.y * xv.x; a0.y += m.y * xv.y;
    }
    a0.x += a1.x; a0.y += a1.y;
    reinterpret_cast<float2*>(ax)[(size_t)grow * 64 + lane] = a0;
}

__global__ __launch_bounds__(256) void scatter_kernel(
    const float* __restrict__ x, const int* __restrict__ rows,
    const int* __restrict__ cols, const float* __restrict__ vals,
    float* __restrict__ ax) {
    const int lane = threadIdx.x & 63;
    int wid = (blockIdx.x * blockDim.x + threadIdx.x) >> 6;
    const int nw = (gridDim.x * blockDim.x) >> 6;
    for (int e = wid; e < TOTEDGE; e += nw) {
        int b = e / NEDGES;
        int r = rows[e];
        int c = cols[e];
        float v = vals[e];
        const float2 m =
            reinterpret_cast<const float2*>(x + (size_t)(b * NNODES + c) * CH)[lane];
        float* dst = ax + (size_t)(b * NNODES + r) * CH + 2 * lane;
        atomicAdd(dst,     v * m.x);
        atomicAdd(dst + 1, v * m.y);
    }
}

// ---------------------------------------------------------------------------
extern "C" void kernel_launch(void* const* d_in, const int* in_sizes, int n_in,
                              void* d_out, int out_size, void* d_ws, size_t ws_size,
                              hipStream_t stream) {
    const float* x    = (const float*)d_in[0];
    const int*   rows = (const int*)  d_in[1];
    const int*   cols = (const int*)  d_in[2];
    const float* vals = (const float*)d_in[3];
    const float* W    = (const float*)d_in[4];
    const float* bias = (const float*)d_in[5];
    float* out = (float*)d_out;

    // ws layout: cnt | row_ptr(+pad) | cursor | bsum | ebsum | edata | xw
    const size_t off_cnt    = 0;
    const size_t off_rowptr = off_cnt    + (size_t)TOTROWS * 4;          // 320000
    const size_t off_cursor = off_rowptr + (size_t)(TOTROWS + 8) * 4;    // 640032
    const size_t off_bsum   = off_cursor + (size_t)TOTROWS * 4;          // 960032
    const size_t off_ebsum  = off_bsum   + (size_t)512 * 4;
    const size_t off_edata  = off_ebsum  + (size_t)512 * 4;              // 964128 -> pad to 16
    const size_t off_edataA = (off_edata + 15) & ~(size_t)15;
    const size_t off_xw     = off_edataA + (size_t)TOTEDGE * 8;          // +20.48MB
    const size_t off_xwA    = (off_xw + 15) & ~(size_t)15;
    const size_t need_full  = off_xwA + (size_t)TOTROWS * CH * 4;        // ~62.5MB
    const size_t need_csr   = off_edataA + (size_t)TOTEDGE * 8;

    int*    cnt     = (int*)   ((char*)d_ws + off_cnt);
    int*    row_ptr = (int*)   ((char*)d_ws + off_rowptr);
    int*    cursor  = (int*)   ((char*)d_ws + off_cursor);
    int*    bsum    = (int*)   ((char*)d_ws + off_bsum);
    int*    ebsum   = (int*)   ((char*)d_ws + off_ebsum);
    float2* edata   = (float2*)((char*)d_ws + off_edataA);
    float*  xw      = (float*) ((char*)d_ws + off_xwA);

    if (ws_size >= need_csr) {
        zero_int_kernel<<<SCAN_BLOCKS, 256, 0, stream>>>(cnt, TOTROWS);
        hist_kernel<<<TOTEDGE / 4 / 256, 256, 0, stream>>>(rows, cnt);
        scan1_kernel<<<SCAN_BLOCKS, 256, 0, stream>>>(cnt, bsum);
        scan2_kernel<<<1, 512, 0, stream>>>(bsum, ebsum);
        scan3_kernel<<<SCAN_BLOCKS, 256, 0, stream>>>(cnt, ebsum, row_ptr, cursor);
        reorder_kernel<<<TOTEDGE / 4 / 256, 256, 0, stream>>>(rows, cols, vals,
                                                              cursor, edata);
        if (ws_size >= need_full) {
            xw_kernel<<<2048, 256, 0, stream>>>(x, W, xw);
            gather_fused_kernel<<<TOTROWS / 4, 256, 0, stream>>>(xw, row_ptr,
                                                                 edata, bias, out);
        } else {
            gather_plain_kernel<<<TOTROWS / 4, 256, 0, stream>>>(x, row_ptr,
                                                                 edata, out);
            transform_kernel<<<2048, 256, 0, stream>>>(out, W, bias, TOTROWS);
        }
    } else {
        zero_f4_kernel<<<2048, 256, 0, stream>>>(out, out_size / 4);
        scatter_kernel<<<20480, 256, 0, stream>>>(x, rows, cols, vals, out);
        transform_kernel<<<2048, 256, 0, stream>>>(out, W, bias, TOTROWS);
    }
}